// Round 12
// baseline (16056.931 us; speedup 1.0000x reference)
//
#include <hip/hip_runtime.h>

typedef float v2f __attribute__((ext_vector_type(2)));
typedef unsigned long long ull;

// Problem dims
#define B_Q 128
#define T_Q 1024
#define I_Q 256
#define H_Q 512

// Partition (r12 = r10/r11 geometry): 16 groups x 8 batches; 64 slices/group
// x 8 h-cols; 1024 WGs x 256 thr -> 4 WGs/CU (16 waves/CU, 4 waves/SIMD,
// co-resident WGs from 4 DIFFERENT groups -> 4 independent streams/SIMD).
//
// ATTRIBUTE LAW (r0-r11 data, 6 configs): ANY waves-per-eu hint (launch_bounds
// 2nd arg OR amdgpu_waves_per_eu) simultaneously (a) caps the allocator at
// 256/min arch-VGPRs and (b) caps DISPATCH at min waves/SIMD (r3: VGPR=108,
// 1024 WGs, LDS ok -> still 2/CU). The knobs are locked: 4 waves/SIMD via
// hints forces a 64-reg budget -> ~40-reg spill (body needs ~108; weights=72).
// r12 FIX: NO waves-per-eu metadata at all. __launch_bounds__(256) single-arg
// sets only flat-workgroup-size; amdgpu_num_vgpr(128) stays as an upper cap.
// Residency then follows the HW law (m69: 4 waves/SIMD at <=128 VGPRs).
//
// BOUNDED FALLBACK: groups occupy contiguous wg blocks (g = wg>>6) and all
// sync/retirement is per-group (G16) -> correct at ANY residency >= 1 group
// (2/CU: groups 0-7 then 8-15, two shifts; 3/CU: 0-11 then 12-15).
// SYNC: r6/r7-proven per-WG flag STORES (no RMW) + parallel poll, 16-bit
// flags (1024 flags = 2KB of d_ws), polled as 512 packed u32.
#define NGR    16
#define BG     8
#define JW     8
#define NWG    1024
#define NTHR   256
#define WPG    64                        // WGs (slices) per group
#define C1     (B_Q * 4 * H_Q)           // copy-1 offset in out (262144 floats)

// LDS: h tile chunked: 8 rows x 64 chunks x (8 floats + 2 pad), + transpose buf
#define CH_STR  10
#define ROW_STR 640                      // 64*10, multiple of 32 -> XOR-row bank-invariant
#define HT_FLOATS (BG * ROW_STR)         // 5120
#define LDS_FLOATS (HT_FLOATS + BG * 9)  // + [8][9] transpose buf
#define LDS_BYTES  (LDS_FLOATS * 4)      // 20768 B -> 4 WGs/CU = 83KB of 160KB

// ---- cross-lane partner fetch, compile-time ctrl (DPP for 1,2,8; swizzle 4,16)
template<int M>
__device__ __forceinline__ float partner(float t) {
    if constexpr (M == 16)
        return __int_as_float(__builtin_amdgcn_ds_swizzle(__float_as_int(t), 0x401F));
    else if constexpr (M == 8)
        return __int_as_float(__builtin_amdgcn_update_dpp(0, __float_as_int(t), 0x128, 0xF, 0xF, true)); // row_ror:8 = xor8
    else if constexpr (M == 4)
        return __int_as_float(__builtin_amdgcn_ds_swizzle(__float_as_int(t), 0x101F));
    else if constexpr (M == 2)
        return __int_as_float(__builtin_amdgcn_update_dpp(0, __float_as_int(t), 0x4E, 0xF, 0xF, true));  // quad_perm [2,3,0,1]
    else
        return __int_as_float(__builtin_amdgcn_update_dpp(0, __float_as_int(t), 0xB1, 0xF, 0xF, true));  // quad_perm [1,0,3,2]
}

// ---- phase-1 butterfly (linear slots, 8 batches; r9-proven): fold ^16 and ^8
// symmetric (both partners hold the same batch set), then reduce-scatter
// ^4..^1 with keep/send selects. After: v[0] = sum for batch (kg & 7).
template<int M, int N>
__device__ __forceinline__ void bstage(float* v, bool hi) {
    #pragma unroll
    for (int i = 0; i < N / 2; ++i) {
        float keep = hi ? v[i + N / 2] : v[i];
        float send = hi ? v[i]         : v[i + N / 2];
        v[i] = keep + partner<M>(send);
    }
}
__device__ __forceinline__ void bflychunk8(float* v, int kg) {
    #pragma unroll
    for (int i = 0; i < 8; ++i) v[i] += partner<16>(v[i]);
    #pragma unroll
    for (int i = 0; i < 8; ++i) v[i] += partner<8>(v[i]);
    bstage<4, 8>(v, (kg & 4) != 0);
    bstage<2, 4>(v, (kg & 2) != 0);
    bstage<1, 2>(v, (kg & 1) != 0);
}

// ---- phase-2 butterfly (XOR slots, select-free; r9-proven): slot i of lane
// kg holds batch (i ^ (kg&7)); every stage v[i] += partner<M>(v[i+M]); the
// ^8 and ^16 folds are symmetric. After: v[0] = sum for batch (kg & 7).
__device__ __forceinline__ void bfly8x(float* v) {
    #pragma unroll
    for (int i = 0; i < 4; ++i) v[i] += partner<4>(v[i + 4]);
    v[0] += partner<2>(v[2]);
    v[1] += partner<2>(v[3]);
    v[0] += partner<1>(v[1]);
    v[0] += partner<8>(v[0]);
    v[0] += partner<16>(v[0]);
}

// fast gates: v_exp_f32 (base-2) + v_rcp_f32; saturating tails exact
__device__ __forceinline__ float fsig(float x) {
    return __builtin_amdgcn_rcpf(1.f + __builtin_amdgcn_exp2f(-1.44269504088896f * x));
}
__device__ __forceinline__ float ftanh(float x) {
    return 1.f - 2.f * __builtin_amdgcn_rcpf(1.f + __builtin_amdgcn_exp2f(2.88539008177793f * x));
}

extern "C" __global__ void __launch_bounds__(NTHR)
__attribute__((amdgpu_num_vgpr(128)))   // upper cap only; NO waves-per-eu hint
gru_scan_kernel(const float* __restrict__ x,
                const float* __restrict__ h0,
                const float* __restrict__ Wih,
                const float* __restrict__ bih,
                const float* __restrict__ Whh,
                const float* __restrict__ bhh,
                float* __restrict__ out,
                int* __restrict__ flags)   // d_ws: NWG u16 flags (2KB), memset-0 by host
{
    extern __shared__ float lds[];
    float* Ht   = lds;                 // [BG][ROW_STR] chunked h(t-1)
    float* tbuf = lds + HT_FLOATS;     // [BG][9] publish transpose

    const int wg  = blockIdx.x;
    const int g   = wg >> 6;              // group 0..15 (contiguous wg block!)
    const int s   = wg & 63;              // slice 0..63
    const int tid = threadIdx.x;
    const int j   = tid >> 5;             // 0..7 local col
    const int kg  = tid & 31;             // 0..31 k-group
    const int jg  = s * JW + j;           // global h-col
    const int c7  = kg & 7;               // b_own within group

    // Per-group hbuf scratch inside the group's OWN copy-1 output region:
    // out[C1 + g*16384 .. +8192). Only group g touches it; fully overwritten
    // by the group's own epilogue after its done-spin -> occupancy-safe.
    float* hbuf = out + C1 + (size_t)g * (BG * 4 * H_Q);   // 2 parity x [BG][H_Q]
    unsigned short* gflg = (unsigned short*)flags + g * WPG;  // 64 u16 flags
    const unsigned*  gpoll = (const unsigned*)flags + g * 32; // same, as 32 u32

    // ---- W slices into registers (v2f for packed fp32 fma)
    v2f wh[3][8];   // hh: k in [8kg,8kg+8) U [256+8kg, 256+8kg+8)
    v2f wi[3][4];   // ih: k in [8kg,8kg+8)
    #pragma unroll
    for (int gt = 0; gt < 3; ++gt) {
        const float* wr = Whh + (size_t)(gt * H_Q + jg) * H_Q + 8 * kg;
        float4 t0 = *(const float4*)(wr);
        float4 t1 = *(const float4*)(wr + 4);
        float4 t2 = *(const float4*)(wr + 256);
        float4 t3 = *(const float4*)(wr + 260);
        wh[gt][0] = (v2f){t0.x, t0.y}; wh[gt][1] = (v2f){t0.z, t0.w};
        wh[gt][2] = (v2f){t1.x, t1.y}; wh[gt][3] = (v2f){t1.z, t1.w};
        wh[gt][4] = (v2f){t2.x, t2.y}; wh[gt][5] = (v2f){t2.z, t2.w};
        wh[gt][6] = (v2f){t3.x, t3.y}; wh[gt][7] = (v2f){t3.z, t3.w};
        const float* wx = Wih + (size_t)(gt * H_Q + jg) * I_Q + 8 * kg;
        float4 u0 = *(const float4*)(wx);
        float4 u1 = *(const float4*)(wx + 4);
        wi[gt][0] = (v2f){u0.x, u0.y}; wi[gt][1] = (v2f){u0.z, u0.w};
        wi[gt][2] = (v2f){u1.x, u1.y}; wi[gt][3] = (v2f){u1.z, u1.w};
    }

    const float br = bih[jg]           + bhh[jg];
    const float bz = bih[H_Q + jg]     + bhh[H_Q + jg];
    const float bin = bih[2 * H_Q + jg], bhn = bhh[2 * H_Q + jg];

    const size_t xstr_b = (size_t)T_Q * I_Q;
    const float* xbase  = x + (size_t)(g * BG) * xstr_b + 8 * kg;

    float lr = 0.f, lz = 0.f, ln = 0.f, lh = 0.f;

    for (int t = 1; t <= T_Q; ++t) {
        // ---- phase 1: x partials, LINEAR slots (slot i = batch i) -> each
        // load instruction is row-contiguous across lanes (coalesced, r7).
        float pr[BG], pz[BG], pn[BG];
        const float* xt = xbase + (size_t)(t - 1) * I_Q;
        #pragma unroll
        for (int i = 0; i < BG; ++i) {
            const float* xp = xt + (size_t)i * xstr_b;
            float4 xa4 = *(const float4*)(xp);
            float4 xb4 = *(const float4*)(xp + 4);
            v2f x0 = (v2f){xa4.x, xa4.y}, x1 = (v2f){xa4.z, xa4.w};
            v2f x2 = (v2f){xb4.x, xb4.y}, x3 = (v2f){xb4.z, xb4.w};
            v2f sr = x0 * wi[0][0] + x1 * wi[0][1] + x2 * wi[0][2] + x3 * wi[0][3];
            v2f sz = x0 * wi[1][0] + x1 * wi[1][1] + x2 * wi[1][2] + x3 * wi[1][3];
            v2f sn = x0 * wi[2][0] + x1 * wi[2][1] + x2 * wi[2][2] + x3 * wi[2][3];
            pr[i] = sr.x + sr.y;
            pz[i] = sz.x + sz.y;
            pn[i] = sn.x + sn.y;
        }
        bflychunk8(pr, kg); bflychunk8(pz, kg); bflychunk8(pn, kg);
        const float oxr = pr[0], oxz = pz[0], oxn = pn[0];

        // ---- acquire h(t-1) into LDS (contiguous global -> chunked LDS)
        if (t == 1) {
            const ull* src = (const ull*)(h0 + (size_t)(g * BG) * H_Q);
            #pragma unroll
            for (int i = 0; i < BG; ++i) {
                int q = tid + i * NTHR;            // 0..2047
                int b = q >> 8, qr = q & 255;
                ull v = src[q];
                *(ull*)(Ht + b * ROW_STR + (qr >> 2) * CH_STR
                        + ((qr & 3) << 1)) = v;
            }
        } else {
            // 32 threads poll 32 packed u32 (= 64 u16 flags) IN PARALLEL,
            // pure loads, no RMW: exit when both packed slices published t-1.
            if (tid < 32) {
                int cnt = 0;
                const unsigned want = (unsigned)(t - 1);
                for (;;) {
                    unsigned u = __hip_atomic_load(gpoll + tid, __ATOMIC_RELAXED,
                                                   __HIP_MEMORY_SCOPE_AGENT);
                    unsigned lo = u & 0xFFFFu, hi = u >> 16;
                    if (lo >= want && hi >= want) break;
                    __builtin_amdgcn_s_sleep(1);
                    if (++cnt > 100000000) break;   // hang guard
                }
            }
            __syncthreads();
            const ull* src = (const ull*)
                (hbuf + (size_t)((t - 1) & 1) * (BG * H_Q));
            #pragma unroll
            for (int i = 0; i < BG; ++i) {
                int q = tid + i * NTHR;
                int b = q >> 8, qr = q & 255;
                ull v = __hip_atomic_load(src + q, __ATOMIC_RELAXED,
                                          __HIP_MEMORY_SCOPE_AGENT);
                *(ull*)(Ht + b * ROW_STR + (qr >> 2) * CH_STR
                        + ((qr & 3) << 1)) = v;
            }
        }
        __syncthreads();

        // ---- phase 2: h partials, XOR slots (row i ^ c7 in LDS; ROW_STR is
        // a multiple of 32 so the XOR row leaves the bank pattern unchanged)
        #pragma unroll
        for (int i = 0; i < BG; ++i) {
            const float* hp = Ht + (i ^ c7) * ROW_STR + CH_STR * kg;
            v2f a0 = *(const v2f*)(hp);
            v2f a1 = *(const v2f*)(hp + 2);
            v2f a2 = *(const v2f*)(hp + 4);
            v2f a3 = *(const v2f*)(hp + 6);
            const float* hq = hp + 32 * CH_STR;   // chunk kg+32: k = 256+8kg
            v2f c0 = *(const v2f*)(hq);
            v2f c1 = *(const v2f*)(hq + 2);
            v2f c2 = *(const v2f*)(hq + 4);
            v2f c3 = *(const v2f*)(hq + 6);
            v2f sr = a0 * wh[0][0] + a1 * wh[0][1] + a2 * wh[0][2] + a3 * wh[0][3]
                   + c0 * wh[0][4] + c1 * wh[0][5] + c2 * wh[0][6] + c3 * wh[0][7];
            v2f sz = a0 * wh[1][0] + a1 * wh[1][1] + a2 * wh[1][2] + a3 * wh[1][3]
                   + c0 * wh[1][4] + c1 * wh[1][5] + c2 * wh[1][6] + c3 * wh[1][7];
            v2f sn = a0 * wh[2][0] + a1 * wh[2][1] + a2 * wh[2][2] + a3 * wh[2][3]
                   + c0 * wh[2][4] + c1 * wh[2][5] + c2 * wh[2][6] + c3 * wh[2][7];
            pr[i] = sr.x + sr.y;
            pz[i] = sz.x + sz.y;
            pn[i] = sn.x + sn.y;
        }
        bfly8x(pr); bfly8x(pz); bfly8x(pn);

        // previous h for this thread's (b_own = c7, col jg)
        float hx = Ht[c7 * ROW_STR + (jg >> 3) * CH_STR + (jg & 7)];

        float rg = fsig(oxr + pr[0] + br);
        float zg = fsig(oxz + pz[0] + bz);
        float ng = ftanh(oxn + bin + rg * (pn[0] + bhn));
        float hn = (1.f - zg) * ng + zg * hx;

        // ---- publish: transpose through LDS, contiguous stores by wave 0
        // (1 float/lane). Store + vmcnt(0) + u16 flag STORE (no RMW) all
        // inside wave 0 (vmcnt is per-wave) -> no trailing __syncthreads;
        // next iteration's acquire barrier orders the rest.
        if (kg < 8) tbuf[kg * 9 + j] = hn;   // kg == batch for kg<8
        __syncthreads();
        if (tid < BG * JW) {                  // tid < 64: all of wave 0
            float* dst = hbuf + (size_t)(t & 1) * (BG * H_Q);
            int b = tid >> 3, jl = tid & 7;
            __hip_atomic_store(dst + b * H_Q + s * JW + jl, tbuf[b * 9 + jl],
                               __ATOMIC_RELAXED, __HIP_MEMORY_SCOPE_AGENT);
            asm volatile("s_waitcnt vmcnt(0)" ::: "memory");
            if (tid == 0)
                __hip_atomic_store(gflg + s, (unsigned short)t,
                                   __ATOMIC_RELAXED, __HIP_MEMORY_SCOPE_AGENT);
        }

        lr = rg; lz = zg; ln = ng; lh = hn;
    }

    // ---- per-group done: all 64 of this group's flags hit T -> all WGs
    // published step T, hence all hbuf reads finished. Epilogue overwrites
    // (only) this group's own regions, including its hbuf scratch.
    if (tid < 32) {
        int cnt = 0;
        for (;;) {
            unsigned u = __hip_atomic_load(gpoll + tid, __ATOMIC_RELAXED,
                                           __HIP_MEMORY_SCOPE_AGENT);
            unsigned lo = u & 0xFFFFu, hi = u >> 16;
            if (lo >= (unsigned)T_Q && hi >= (unsigned)T_Q) break;
            __builtin_amdgcn_s_sleep(2);
            if (++cnt > 100000000) break;   // hang guard
        }
    }
    __syncthreads();

    if (kg < 8) {
        size_t o = (size_t)(g * BG + kg) * (4 * H_Q);
        out[o + jg]             = lr;
        out[o + H_Q + jg]       = lz;
        out[o + 2 * H_Q + jg]   = ln;
        out[o + 3 * H_Q + jg]   = lh;
        size_t o2 = o + (size_t)C1;
        out[o2 + jg]            = lr;
        out[o2 + H_Q + jg]      = lz;
        out[o2 + 2 * H_Q + jg]  = ln;
        out[o2 + 3 * H_Q + jg]  = lh;
    }
}

extern "C" void kernel_launch(void* const* d_in, const int* in_sizes, int n_in,
                              void* d_out, int out_size, void* d_ws, size_t ws_size,
                              hipStream_t stream) {
    const float* x   = (const float*)d_in[0];
    const float* h0  = (const float*)d_in[1];
    const float* Wih = (const float*)d_in[2];
    const float* bih = (const float*)d_in[3];
    const float* Whh = (const float*)d_in[4];
    const float* bhh = (const float*)d_in[5];
    float* outp  = (float*)d_out;
    int*   flags = (int*)d_ws;   // NWG u16 step flags (2 KB)

    (void)in_sizes; (void)n_in; (void)ws_size; (void)out_size;

    // zero the per-WG u16 flags every launch (stream-ordered, capture-safe)
    hipMemsetAsync(d_ws, 0, NWG * sizeof(unsigned short), stream);

    gru_scan_kernel<<<dim3(NWG), dim3(NTHR), LDS_BYTES, stream>>>(
        x, h0, Wih, bih, Whh, bhh, outp, flags);
}

// Round 13
// 12494.223 us; speedup vs baseline: 1.2851x; 1.2851x over previous
//
#include <hip/hip_runtime.h>

typedef float v2f __attribute__((ext_vector_type(2)));
typedef unsigned long long ull;

// Problem dims
#define B_Q 128
#define T_Q 1024
#define I_Q 256
#define H_Q 512

// Partition (r13 = r7 base, proven 9.4ms): 8 groups x 16 batches; 64 slices x
// 8 h-cols; 512 WGs x 256 thr; launch_bounds(256,2) -> 2 WGs/CU, fully
// resident (RESIDENCY LAW r0-r12: dispatch follows the waves hint; any
// 4-waves declaration forces a 64-reg budget -> spill (weights=72 regs) ->
// occupancy axis is structurally closed; r12 no-hint ran 2 shifts, 16ms).
//
// r13 CHANGE — X-TILE LDS DEDUP: threads (j,kg) sharing kg re-read the SAME
// x bytes 8x (once per j). Per WG-step: 128KB x + 32KB h = 160KB from L2;
// x512 WGs = 84MB/step ~ 2.4us at L2 BW — the biggest stall term. Now the
// 16KB x-tile is staged into LDS once (64B/thread, issued into regs BEFORE
// the spin so HBM/L2 latency hides under it), and phase 1 reads LDS.
// L2/WG-step: 160KB -> 48KB. Bonus: phase-1 batch scatter now lives in LDS
// (bank-invariant, XROW_STR%32==0) -> select-free XOR butterfly in BOTH
// phases (drops ~90 cndmask ops/step vs r7's bflychunk).
//
// SYNC (r6/r7 proven): per-WG flag STORES (no RMW) + 64-thread parallel poll.
// Correctness PER-GROUP only (G16): per-group flags + retirement; hbuf
// scratch in the group's OWN copy-1 output region -> occupancy-safe.
#define NGR    8
#define BG     16
#define JW     8
#define NWG    512
#define NTHR   256
#define WPG    (NWG / NGR)               // 64 WGs per group
#define C1     (B_Q * 4 * H_Q)           // copy-1 offset in out (262144 floats)

// LDS: h tile [16][64 chunks][8+2 pad] + x tile [16][32 chunks][8+2 pad] + tbuf
#define CH_STR  10
#define ROW_STR 640                      // 64*10, %32==0 -> XOR-row bank-invariant
#define XROW_STR 320                     // 32*10, %32==0 -> XOR-row bank-invariant
#define HT_FLOATS (BG * ROW_STR)         // 10240
#define XT_FLOATS (BG * XROW_STR)        // 5120
#define TB_FLOATS (BG * 9)               // 144 (stride 9: conflict-free transpose)
#define LDS_FLOATS (HT_FLOATS + XT_FLOATS + TB_FLOATS)
#define LDS_BYTES  (LDS_FLOATS * 4)      // 62016 B -> 2 WGs/CU = 124KB of 160KB

// ---- cross-lane partner fetch, compile-time ctrl (DPP for 1,2,8; swizzle 4,16)
template<int M>
__device__ __forceinline__ float partner(float t) {
    if constexpr (M == 16)
        return __int_as_float(__builtin_amdgcn_ds_swizzle(__float_as_int(t), 0x401F));
    else if constexpr (M == 8)
        return __int_as_float(__builtin_amdgcn_update_dpp(0, __float_as_int(t), 0x128, 0xF, 0xF, true)); // row_ror:8 = xor8
    else if constexpr (M == 4)
        return __int_as_float(__builtin_amdgcn_ds_swizzle(__float_as_int(t), 0x101F));
    else if constexpr (M == 2)
        return __int_as_float(__builtin_amdgcn_update_dpp(0, __float_as_int(t), 0x4E, 0xF, 0xF, true));  // quad_perm [2,3,0,1]
    else
        return __int_as_float(__builtin_amdgcn_update_dpp(0, __float_as_int(t), 0xB1, 0xF, 0xF, true));  // quad_perm [1,0,3,2]
}

// ---- XOR-slot butterfly, 16 slots (r6/r7-proven in phase 2; now both
// phases): slot i of lane kg holds batch (i ^ (kg&15)); every stage is
// uniformly v[i] += partner<M>(v[i+M]) -- zero cndmask selects. Scatter
// (8,4,2,1) first, then the symmetric ^16 fold on the single survivor.
// After: EVERY lane kg has v[0] = full 32-lane sum for batch (kg & 15).
__device__ __forceinline__ void bfly16(float* v) {
    #pragma unroll
    for (int i = 0; i < 8; ++i) v[i] += partner<8>(v[i + 8]);
    #pragma unroll
    for (int i = 0; i < 4; ++i) v[i] += partner<4>(v[i + 4]);
    v[0] += partner<2>(v[2]);
    v[1] += partner<2>(v[3]);
    v[0] += partner<1>(v[1]);
    v[0] += partner<16>(v[0]);    // symmetric fold: same (kg&15) on both sides
}

// fast gates: v_exp_f32 (base-2) + v_rcp_f32; saturating tails exact
__device__ __forceinline__ float fsig(float x) {
    return __builtin_amdgcn_rcpf(1.f + __builtin_amdgcn_exp2f(-1.44269504088896f * x));
}
__device__ __forceinline__ float ftanh(float x) {
    return 1.f - 2.f * __builtin_amdgcn_rcpf(1.f + __builtin_amdgcn_exp2f(2.88539008177793f * x));
}

extern "C" __global__ void __launch_bounds__(NTHR, 2)
__attribute__((amdgpu_num_vgpr(128)))   // fail-safe: spill beats residency loss
gru_scan_kernel(const float* __restrict__ x,
                const float* __restrict__ h0,
                const float* __restrict__ Wih,
                const float* __restrict__ bih,
                const float* __restrict__ Whh,
                const float* __restrict__ bhh,
                float* __restrict__ out,
                int* __restrict__ flags)   // d_ws: NWG per-WG flags, memset-0 by host
{
    extern __shared__ float lds[];
    float* Ht   = lds;                       // [BG][ROW_STR]  chunked h(t-1)
    float* Xt   = lds + HT_FLOATS;           // [BG][XROW_STR] chunked x(t) tile
    float* tbuf = lds + HT_FLOATS + XT_FLOATS;   // [BG][9] publish transpose

    const int wg  = blockIdx.x;
    const int g   = wg >> 6;              // group 0..7 (r7 mapping)
    const int s   = wg & 63;              // slice 0..63
    const int tid = threadIdx.x;
    const int j   = tid >> 5;             // 0..7 local col
    const int kg  = tid & 31;             // 0..31 k-group
    const int jg  = s * JW + j;           // global h-col
    const int c15 = kg & 15;              // XOR-slot key == b_own

    // Per-group hbuf scratch inside the group's OWN copy-1 output region:
    // out[C1 + g*32768 .. +16384). Only group g touches it; fully overwritten
    // by the group's own epilogue after its done-spin -> occupancy-safe.
    float* hbuf = out + C1 + (size_t)g * (BG * 4 * H_Q);   // 2 parity x [BG][H_Q]
    int*   gflags = flags + g * WPG;      // this group's 64 per-WG flags

    // ---- W slices into registers (v2f for packed fp32 fma)
    v2f wh[3][8];   // hh: k in [8kg,8kg+8) U [256+8kg, 256+8kg+8)
    v2f wi[3][4];   // ih: k in [8kg,8kg+8)
    #pragma unroll
    for (int gt = 0; gt < 3; ++gt) {
        const float* wr = Whh + (size_t)(gt * H_Q + jg) * H_Q + 8 * kg;
        float4 t0 = *(const float4*)(wr);
        float4 t1 = *(const float4*)(wr + 4);
        float4 t2 = *(const float4*)(wr + 256);
        float4 t3 = *(const float4*)(wr + 260);
        wh[gt][0] = (v2f){t0.x, t0.y}; wh[gt][1] = (v2f){t0.z, t0.w};
        wh[gt][2] = (v2f){t1.x, t1.y}; wh[gt][3] = (v2f){t1.z, t1.w};
        wh[gt][4] = (v2f){t2.x, t2.y}; wh[gt][5] = (v2f){t2.z, t2.w};
        wh[gt][6] = (v2f){t3.x, t3.y}; wh[gt][7] = (v2f){t3.z, t3.w};
        const float* wx = Wih + (size_t)(gt * H_Q + jg) * I_Q + 8 * kg;
        float4 u0 = *(const float4*)(wx);
        float4 u1 = *(const float4*)(wx + 4);
        wi[gt][0] = (v2f){u0.x, u0.y}; wi[gt][1] = (v2f){u0.z, u0.w};
        wi[gt][2] = (v2f){u1.x, u1.y}; wi[gt][3] = (v2f){u1.z, u1.w};
    }

    const float br = bih[jg]           + bhh[jg];
    const float bz = bih[H_Q + jg]     + bhh[H_Q + jg];
    const float bin = bih[2 * H_Q + jg], bhn = bhh[2 * H_Q + jg];

    const size_t xstr_b = (size_t)T_Q * I_Q;
    const float* xg = x + (size_t)(g * BG) * xstr_b;   // group's batch block

    float lr = 0.f, lz = 0.f, ln = 0.f, lh = 0.f;

    for (int t = 1; t <= T_Q; ++t) {
        // ---- issue x-tile loads into REGISTERS first (64B/thread, coalesced;
        // their L2/HBM latency hides under the spin below). Tile = 16 batches
        // x 256 floats; thread u-th load: ull q = tid + u*256.
        ull xv[8];
        {
            const float* xtf = xg + (size_t)(t - 1) * I_Q;
            #pragma unroll
            for (int u = 0; u < 8; ++u) {
                int q = tid + u * NTHR;            // 0..2047 (ull index)
                int b = q >> 7, off = q & 127;     // batch, ull-offset in row
                xv[u] = *(const ull*)(xtf + (size_t)b * xstr_b + (off << 1));
            }
        }

        // ---- acquire: spin for h(t-1) published (64 parallel flag loads)
        if (t > 1) {
            if (tid < WPG) {
                int cnt = 0;
                while (__hip_atomic_load(gflags + tid, __ATOMIC_RELAXED,
                                         __HIP_MEMORY_SCOPE_AGENT) < t - 1) {
                    __builtin_amdgcn_s_sleep(1);
                    if (++cnt > 100000000) break;   // hang guard
                }
            }
        }
        __syncthreads();   // flag-ack; also fences prev iter's Xt/Ht readers

        // ---- stage x tile: regs -> chunked LDS (mirrors h-chunk layout)
        #pragma unroll
        for (int u = 0; u < 8; ++u) {
            int q = tid + u * NTHR;
            int b = q >> 7, f = (q & 127) << 1;    // float offset 0..254
            *(ull*)(Xt + b * XROW_STR + (f >> 3) * CH_STR + (f & 7)) = xv[u];
        }

        // ---- stage h(t-1): global (h0 or hbuf) -> chunked LDS
        if (t == 1) {
            const ull* src = (const ull*)(h0 + (size_t)(g * BG) * H_Q);
            #pragma unroll
            for (int i = 0; i < BG; ++i) {
                int q = tid + i * NTHR;            // 0..4095
                int b = q >> 8, qr = q & 255;
                ull v = src[q];
                *(ull*)(Ht + b * ROW_STR + (qr >> 2) * CH_STR
                        + ((qr & 3) << 1)) = v;
            }
        } else {
            const ull* src = (const ull*)
                (hbuf + (size_t)((t - 1) & 1) * (BG * H_Q));
            #pragma unroll
            for (int i = 0; i < BG; ++i) {
                int q = tid + i * NTHR;
                int b = q >> 8, qr = q & 255;
                ull v = __hip_atomic_load(src + q, __ATOMIC_RELAXED,
                                          __HIP_MEMORY_SCOPE_AGENT);
                *(ull*)(Ht + b * ROW_STR + (qr >> 2) * CH_STR
                        + ((qr & 3) << 1)) = v;
            }
        }
        __syncthreads();

        // ---- phase 1: x partials from LDS, XOR slots (row i^c15 of Xt;
        // XROW_STR % 32 == 0 -> bank-invariant scatter, free). Chunk kg
        // holds k in [8kg, 8kg+8) -- exactly this thread's wi slice.
        float pr[BG], pz[BG], pn[BG];
        #pragma unroll
        for (int i = 0; i < BG; ++i) {
            const float* xp = Xt + (i ^ c15) * XROW_STR + CH_STR * kg;
            v2f x0 = *(const v2f*)(xp);
            v2f x1 = *(const v2f*)(xp + 2);
            v2f x2 = *(const v2f*)(xp + 4);
            v2f x3 = *(const v2f*)(xp + 6);
            v2f sr = x0 * wi[0][0] + x1 * wi[0][1] + x2 * wi[0][2] + x3 * wi[0][3];
            v2f sz = x0 * wi[1][0] + x1 * wi[1][1] + x2 * wi[1][2] + x3 * wi[1][3];
            v2f sn = x0 * wi[2][0] + x1 * wi[2][1] + x2 * wi[2][2] + x3 * wi[2][3];
            pr[i] = sr.x + sr.y;
            pz[i] = sz.x + sz.y;
            pn[i] = sn.x + sn.y;
        }
        bfly16(pr); bfly16(pz); bfly16(pn);
        const float oxr = pr[0], oxz = pz[0], oxn = pn[0];

        // ---- phase 2: h partials, XOR slots (row i^c15 of Ht; r7-proven)
        #pragma unroll
        for (int i = 0; i < BG; ++i) {
            const float* hp = Ht + (i ^ c15) * ROW_STR + CH_STR * kg;
            v2f a0 = *(const v2f*)(hp);
            v2f a1 = *(const v2f*)(hp + 2);
            v2f a2 = *(const v2f*)(hp + 4);
            v2f a3 = *(const v2f*)(hp + 6);
            const float* hq = hp + 32 * CH_STR;   // chunk kg+32: k = 256+8kg
            v2f c0 = *(const v2f*)(hq);
            v2f c1 = *(const v2f*)(hq + 2);
            v2f c2 = *(const v2f*)(hq + 4);
            v2f c3 = *(const v2f*)(hq + 6);
            v2f sr = a0 * wh[0][0] + a1 * wh[0][1] + a2 * wh[0][2] + a3 * wh[0][3]
                   + c0 * wh[0][4] + c1 * wh[0][5] + c2 * wh[0][6] + c3 * wh[0][7];
            v2f sz = a0 * wh[1][0] + a1 * wh[1][1] + a2 * wh[1][2] + a3 * wh[1][3]
                   + c0 * wh[1][4] + c1 * wh[1][5] + c2 * wh[1][6] + c3 * wh[1][7];
            v2f sn = a0 * wh[2][0] + a1 * wh[2][1] + a2 * wh[2][2] + a3 * wh[2][3]
                   + c0 * wh[2][4] + c1 * wh[2][5] + c2 * wh[2][6] + c3 * wh[2][7];
            pr[i] = sr.x + sr.y;
            pz[i] = sz.x + sz.y;
            pn[i] = sn.x + sn.y;
        }
        bfly16(pr); bfly16(pz); bfly16(pn);

        // previous h for this thread's (b_own = c15, col jg)
        float hx = Ht[c15 * ROW_STR + (jg >> 3) * CH_STR + (jg & 7)];

        float rg = fsig(oxr + pr[0] + br);
        float zg = fsig(oxz + pz[0] + bz);
        float ng = ftanh(oxn + bin + rg * (pn[0] + bhn));
        float hn = (1.f - zg) * ng + zg * hx;

        // ---- publish: transpose through LDS, contiguous stores by wave 0
        // (2 items/lane). Store + vmcnt(0) + per-WG flag STORE (no RMW) all
        // inside wave 0 (vmcnt is per-wave) -> no trailing __syncthreads;
        // next iteration's acquire barrier orders the rest.
        if (kg < 16) tbuf[kg * 9 + j] = hn;   // kg == batch for kg<16
        __syncthreads();
        if (tid < 64) {
            float* dst = hbuf + (size_t)(t & 1) * (BG * H_Q);
            #pragma unroll
            for (int u = 0; u < 2; ++u) {
                int q = tid + u * 64;             // 0..127
                int b = q >> 3, jl = q & 7;
                __hip_atomic_store(dst + b * H_Q + s * JW + jl, tbuf[b * 9 + jl],
                                   __ATOMIC_RELAXED, __HIP_MEMORY_SCOPE_AGENT);
            }
            asm volatile("s_waitcnt vmcnt(0)" ::: "memory");
            if (tid == 0)
                __hip_atomic_store(gflags + s, t, __ATOMIC_RELAXED,
                                   __HIP_MEMORY_SCOPE_AGENT);
        }

        lr = rg; lz = zg; ln = ng; lh = hn;
    }

    // ---- per-group done: all 64 of this group's flags hit T -> all WGs
    // published step T, hence all hbuf reads finished. Epilogue overwrites
    // (only) this group's own regions, including its hbuf scratch.
    if (tid < WPG) {
        int cnt = 0;
        while (__hip_atomic_load(gflags + tid, __ATOMIC_RELAXED,
                                 __HIP_MEMORY_SCOPE_AGENT) < T_Q) {
            __builtin_amdgcn_s_sleep(2);
            if (++cnt > 100000000) break;   // hang guard
        }
    }
    __syncthreads();

    if (kg < 16) {
        size_t o = (size_t)(g * BG + kg) * (4 * H_Q);
        out[o + jg]             = lr;
        out[o + H_Q + jg]       = lz;
        out[o + 2 * H_Q + jg]   = ln;
        out[o + 3 * H_Q + jg]   = lh;
        size_t o2 = o + (size_t)C1;
        out[o2 + jg]            = lr;
        out[o2 + H_Q + jg]      = lz;
        out[o2 + 2 * H_Q + jg]  = ln;
        out[o2 + 3 * H_Q + jg]  = lh;
    }
}

extern "C" void kernel_launch(void* const* d_in, const int* in_sizes, int n_in,
                              void* d_out, int out_size, void* d_ws, size_t ws_size,
                              hipStream_t stream) {
    const float* x   = (const float*)d_in[0];
    const float* h0  = (const float*)d_in[1];
    const float* Wih = (const float*)d_in[2];
    const float* bih = (const float*)d_in[3];
    const float* Whh = (const float*)d_in[4];
    const float* bhh = (const float*)d_in[5];
    float* outp  = (float*)d_out;
    int*   flags = (int*)d_ws;   // NWG per-WG step flags (2 KB)

    (void)in_sizes; (void)n_in; (void)ws_size; (void)out_size;

    // zero the per-WG flags every launch (stream-ordered, capture-safe)
    hipMemsetAsync(d_ws, 0, NWG * sizeof(int), stream);

    gru_scan_kernel<<<dim3(NWG), dim3(NTHR), LDS_BYTES, stream>>>(
        x, h0, Wih, bih, Whh, bhh, outp, flags);
}